// Round 9
// baseline (98.085 us; speedup 1.0000x reference)
//
#include <hip/hip_runtime.h>
#include <math.h>

#define BATCH 512    // post-reshape scan lanes
#define FRAGS 512    // fragments per chain (rpf = 2048/FRAGS = 4 residues)
#define GROUP 32     // fragments per scan group == frags per K1 block
#define NGRP  (FRAGS/GROUP)   // 16
#define BTILE 16     // batch lanes per K1 block
#define RPF   4      // residues per fragment

// Rigid transform: 12 floats, R row-major r[i*3+j], t=[9..11]. x' = Rx + t.
// compose(A,B): A is the EARLIER prefix, B the later. (Verified R5-R7.)
__device__ __forceinline__ void compose(const float* A, const float* B, float* D) {
    float d[12];
    #pragma unroll
    for (int i = 0; i < 3; ++i) {
        #pragma unroll
        for (int j = 0; j < 3; ++j)
            d[i*3+j] = A[i*3+0]*B[0*3+j] + A[i*3+1]*B[1*3+j] + A[i*3+2]*B[2*3+j];
        d[9+i] = A[i*3+0]*B[9] + A[i*3+1]*B[10] + A[i*3+2]*B[11] + A[9+i];
    }
    #pragma unroll
    for (int k = 0; k < 12; ++k) D[k] = d[k];
}

__device__ __forceinline__ void frame_of(
    float ax, float ay, float az,
    float bx, float by, float bz,
    float cx, float cy, float cz,
    float* out /*12*/)
{
    float bcx = cx - bx, bcy = cy - by, bcz = cz - bz;
    float inv = rsqrtf(bcx*bcx + bcy*bcy + bcz*bcz + 1e-12f);
    bcx *= inv; bcy *= inv; bcz *= inv;
    float bax = bx - ax, bay = by - ay, baz = bz - az;
    float nx = bay*bcz - baz*bcy;
    float ny = baz*bcx - bax*bcz;
    float nz = bax*bcy - bay*bcx;
    inv = rsqrtf(nx*nx + ny*ny + nz*nz + 1e-12f);
    nx *= inv; ny *= inv; nz *= inv;
    float mx = ny*bcz - nz*bcy;
    float my = nz*bcx - nx*bcz;
    float mz = nx*bcy - ny*bcx;
    out[0] = bcx; out[1] = mx; out[2] = nx;
    out[3] = bcy; out[4] = my; out[5] = ny;
    out[6] = bcz; out[7] = mz; out[8] = nz;
    out[9] = cx; out[10] = cy; out[11] = cz;
}

__device__ __forceinline__ void nerf_step(
    float ax, float ay, float az,
    float bx, float by, float bz,
    float cx, float cy, float cz,
    float px, float py, float pz,
    float& ox, float& oy, float& oz)
{
    float bcx = cx - bx, bcy = cy - by, bcz = cz - bz;
    float inv = rsqrtf(bcx*bcx + bcy*bcy + bcz*bcz + 1e-12f);
    bcx *= inv; bcy *= inv; bcz *= inv;
    float bax = bx - ax, bay = by - ay, baz = bz - az;
    float nx = bay*bcz - baz*bcy;
    float ny = baz*bcx - bax*bcz;
    float nz = bax*bcy - bay*bcx;
    inv = rsqrtf(nx*nx + ny*ny + nz*nz + 1e-12f);
    nx *= inv; ny *= inv; nz *= inv;
    float mx = ny*bcz - nz*bcy;
    float my = nz*bcx - nx*bcz;
    float mz = nx*bcy - ny*bcx;
    ox = bcx*px + mx*py + nx*pz + cx;
    oy = bcy*px + my*py + ny*pz + cy;
    oz = bcz*px + mz*py + nz*pz + cz;
}

// Per-lane permuted bond constants. Reshape (L,B,3,3)->(3L,B,3) makes scan
// lane b at residue l, step k consume dih flat[l*1536 + 512k + b]; bond-const
// index = (512k+b)%3 -> pattern d = {b%3, (b+2)%3, (b+1)%3}. (Verified R5.)
__device__ __forceinline__ void lane_consts(int b, float* rcl, float* rsl) {
    const float PI = 3.14159265358979323846f;
    float rc[3], rs[3];
    rc[0] = 145.801f * cosf(PI - 2.124f); rs[0] = 145.801f * sinf(PI - 2.124f);
    rc[1] = 152.326f * cosf(PI - 1.941f); rs[1] = 152.326f * sinf(PI - 1.941f);
    rc[2] = 132.868f * cosf(PI - 2.028f); rs[2] = 132.868f * sinf(PI - 2.028f);
    const int d0 = b % 3, d1 = (b + 2) % 3, d2 = (b + 1) % 3;
    rcl[0] = rc[d0]; rcl[1] = rc[d1]; rcl[2] = rc[d2];
    rsl[0] = rs[d0]; rsl[1] = rs[d1]; rsl[2] = rs[d2];
}

// Local chain for (f,b) from canonical init; leaves carry in (a,b,c).
// If out != nullptr also transforms each point by G and stores.
__device__ __forceinline__ void local_chain(
    const float* __restrict__ dih, int f, int b,
    const float* rcl, const float* rsl,
    float& ax, float& ay, float& az,
    float& bx, float& by, float& bz,
    float& cx, float& cy, float& cz,
    const float* G, float* __restrict__ out)
{
    ax = -0.70710678118654752f; ay = 1.22474487139158905f; az = 0.0f;
    bx = -1.41421356237309505f; by = 0.0f; bz = 0.0f;
    cx = 0.0f; cy = 0.0f; cz = 0.0f;

    #pragma unroll
    for (int r = 0; r < RPF; ++r) {
        int l = f * RPF + r;
        const float* src = dih + (size_t)l * (3 * BATCH) + b;
        float dd[3];
        dd[0] = src[0];
        dd[1] = src[BATCH];
        dd[2] = src[2 * BATCH];
        #pragma unroll
        for (int k = 0; k < 3; ++k) {
            float sn, cs;
            __sincosf(dd[k], &sn, &cs);
            float ox, oy, oz;
            nerf_step(ax, ay, az, bx, by, bz, cx, cy, cz,
                      rcl[k], cs * rsl[k], sn * rsl[k], ox, oy, oz);
            ax = bx; ay = by; az = bz;
            bx = cx; by = cy; bz = cz;
            cx = ox; cy = oy; cz = oz;
            if (out) {
                float gx = G[0]*ox + G[1]*oy + G[2]*oz + G[9];
                float gy = G[3]*ox + G[4]*oy + G[5]*oz + G[10];
                float gz = G[6]*ox + G[7]*oy + G[8]*oz + G[11];
                size_t n = (size_t)l * 3 + k;
                float* dst = out + (n * BATCH + b) * 3;
                dst[0] = gx; dst[1] = gy; dst[2] = gz;
            }
        }
    }
}

// K1: block = BTILE b-lanes x GROUP frags (one scan group). Local chain ->
// frame in LDS -> 5-step Hillis-Steele scan -> write inclusive prefixes P.
__global__ void __launch_bounds__(BTILE * GROUP) frames_scan_k(
    const float* __restrict__ dih, float* __restrict__ P)
{
    const int btile = blockIdx.x & (BATCH / BTILE - 1);   // 32 tiles
    const int g     = blockIdx.x / (BATCH / BTILE);       // 16 groups
    const int bsub  = threadIdx.x & (BTILE - 1);
    const int j     = threadIdx.x >> 4;                   // frag within group
    const int f     = g * GROUP + j;
    const int b     = btile * BTILE + bsub;

    __shared__ float S[GROUP * BTILE * 13];               // stride 13: conflict-free
    float* Srow = &S[(size_t)threadIdx.x * 13];

    float rcl[3], rsl[3];
    lane_consts(b, rcl, rsl);

    float ax, ay, az, bx, by, bz, cx, cy, cz;
    local_chain(dih, f, b, rcl, rsl, ax, ay, az, bx, by, bz, cx, cy, cz,
                nullptr, nullptr);

    {
        float h[12];
        frame_of(ax, ay, az, bx, by, bz, cx, cy, cz, h);
        #pragma unroll
        for (int k = 0; k < 12; ++k) Srow[k] = h[k];
    }
    __syncthreads();

    // Hillis-Steele inclusive scan over j (non-commutative, left-compose).
    float tmp[12];
    #pragma unroll
    for (int o = 1; o < GROUP; o <<= 1) {
        const bool act = (j >= o);
        if (act) compose(&S[(size_t)(threadIdx.x - o * BTILE) * 13], Srow, tmp);
        __syncthreads();
        if (act) {
            #pragma unroll
            for (int k = 0; k < 12; ++k) Srow[k] = tmp[k];
        }
        __syncthreads();
    }

    #pragma unroll
    for (int k = 0; k < 12; ++k)
        P[((size_t)f * 12 + k) * BATCH + b] = Srow[k];
}

// K2: thread (f,b), b-fast; f block-uniform. E_g composed inline from group
// totals T_g' = P[GROUP*g'+GROUP-1] (L2-hot, <=NGRP-1 composes);
// G = E_g o P[f-1]; recompute chain, transform, coalesced stores.
__global__ void __launch_bounds__(256) apply_k(
    const float* __restrict__ dih, const float* __restrict__ P,
    float* __restrict__ out)
{
    int t = blockIdx.x * blockDim.x + threadIdx.x;
    int b = t & (BATCH - 1);
    int f = t >> 9;
    if (f >= FRAGS) return;
    int g = f / GROUP, j = f & (GROUP - 1);

    float G[12];
    if (g == 0) {
        G[0]=1.f; G[1]=0.f; G[2]=0.f;
        G[3]=0.f; G[4]=1.f; G[5]=0.f;
        G[6]=0.f; G[7]=0.f; G[8]=1.f;
        G[9]=0.f; G[10]=0.f; G[11]=0.f;
    } else {
        #pragma unroll
        for (int k = 0; k < 12; ++k)
            G[k] = P[((size_t)(GROUP - 1) * 12 + k) * BATCH + b];  // T_0
        for (int gp = 1; gp < g; ++gp) {
            float tg[12];
            int fl = gp * GROUP + GROUP - 1;
            #pragma unroll
            for (int k = 0; k < 12; ++k)
                tg[k] = P[((size_t)fl * 12 + k) * BATCH + b];
            compose(G, tg, G);
        }
    }
    if (j > 0) {
        float p[12];
        #pragma unroll
        for (int k = 0; k < 12; ++k)
            p[k] = P[((size_t)(f - 1) * 12 + k) * BATCH + b];
        compose(G, p, G);
    }

    float rcl[3], rsl[3];
    lane_consts(b, rcl, rsl);

    float ax, ay, az, bx, by, bz, cx, cy, cz;
    local_chain(dih, f, b, rcl, rsl, ax, ay, az, bx, by, bz, cx, cy, cz,
                G, out);
}

extern "C" void kernel_launch(void* const* d_in, const int* in_sizes, int n_in,
                              void* d_out, int out_size, void* d_ws, size_t ws_size,
                              hipStream_t stream) {
    const float* dih = (const float*)d_in[0];
    float* out = (float*)d_out;
    float* P = (float*)d_ws;              // FRAGS*12*BATCH floats (12.6 MB)

    frames_scan_k<<<dim3(NGRP * (BATCH / BTILE)), dim3(BTILE * GROUP), 0, stream>>>(
        dih, P);
    apply_k<<<dim3(FRAGS * BATCH / 256), dim3(256), 0, stream>>>(
        dih, P, out);
    (void)ws_size; (void)n_in; (void)out_size; (void)in_sizes;
}

// Round 10
// 92.080 us; speedup vs baseline: 1.0652x; 1.0652x over previous
//
#include <hip/hip_runtime.h>
#include <math.h>

#define BATCH 512    // post-reshape scan lanes
#define FRAGS 256    // fragments per chain
#define GROUP 16     // fragments per scan group == frags per block
#define NGRP  (FRAGS/GROUP)   // 16 groups
#define BTILE 32     // batch lanes per block
#define NTILE (BATCH/BTILE)   // 16 b-tiles
#define RPF   8      // residues per fragment (L=2048)
#define READY 0x5EADBEEF

// Rigid transform: 12 floats, R row-major r[i*3+j], t=[9..11]. x' = Rx + t.
// compose(A,B): A is the EARLIER prefix, B the later. (Verified R5-R9.)
__device__ __forceinline__ void compose(const float* A, const float* B, float* D) {
    float d[12];
    #pragma unroll
    for (int i = 0; i < 3; ++i) {
        #pragma unroll
        for (int j = 0; j < 3; ++j)
            d[i*3+j] = A[i*3+0]*B[0*3+j] + A[i*3+1]*B[1*3+j] + A[i*3+2]*B[2*3+j];
        d[9+i] = A[i*3+0]*B[9] + A[i*3+1]*B[10] + A[i*3+2]*B[11] + A[9+i];
    }
    #pragma unroll
    for (int k = 0; k < 12; ++k) D[k] = d[k];
}

__device__ __forceinline__ void frame_of(
    float ax, float ay, float az,
    float bx, float by, float bz,
    float cx, float cy, float cz,
    float* out /*12*/)
{
    float bcx = cx - bx, bcy = cy - by, bcz = cz - bz;
    float inv = rsqrtf(bcx*bcx + bcy*bcy + bcz*bcz + 1e-12f);
    bcx *= inv; bcy *= inv; bcz *= inv;
    float bax = bx - ax, bay = by - ay, baz = bz - az;
    float nx = bay*bcz - baz*bcy;
    float ny = baz*bcx - bax*bcz;
    float nz = bax*bcy - bay*bcx;
    inv = rsqrtf(nx*nx + ny*ny + nz*nz + 1e-12f);
    nx *= inv; ny *= inv; nz *= inv;
    float mx = ny*bcz - nz*bcy;
    float my = nz*bcx - nx*bcz;
    float mz = nx*bcy - ny*bcx;
    out[0] = bcx; out[1] = mx; out[2] = nx;
    out[3] = bcy; out[4] = my; out[5] = ny;
    out[6] = bcz; out[7] = mz; out[8] = nz;
    out[9] = cx; out[10] = cy; out[11] = cz;
}

__device__ __forceinline__ void nerf_step(
    float ax, float ay, float az,
    float bx, float by, float bz,
    float cx, float cy, float cz,
    float px, float py, float pz,
    float& ox, float& oy, float& oz)
{
    float bcx = cx - bx, bcy = cy - by, bcz = cz - bz;
    float inv = rsqrtf(bcx*bcx + bcy*bcy + bcz*bcz + 1e-12f);
    bcx *= inv; bcy *= inv; bcz *= inv;
    float bax = bx - ax, bay = by - ay, baz = bz - az;
    float nx = bay*bcz - baz*bcy;
    float ny = baz*bcx - bax*bcz;
    float nz = bax*bcy - bay*bcx;
    inv = rsqrtf(nx*nx + ny*ny + nz*nz + 1e-12f);
    nx *= inv; ny *= inv; nz *= inv;
    float mx = ny*bcz - nz*bcy;
    float my = nz*bcx - nx*bcz;
    float mz = nx*bcy - ny*bcx;
    ox = bcx*px + mx*py + nx*pz + cx;
    oy = bcy*px + my*py + ny*pz + cy;
    oz = bcz*px + mz*py + nz*pz + cz;
}

// Per-lane permuted bond constants. Reshape (L,B,3,3)->(3L,B,3) makes scan
// lane b at residue l, step k consume dih flat[l*1536 + 512k + b]; bond-const
// index = (512k+b)%3 -> pattern d = {b%3, (b+2)%3, (b+1)%3}. (Verified R5.)
__device__ __forceinline__ void lane_consts(int b, float* rcl, float* rsl) {
    const float PI = 3.14159265358979323846f;
    float rc[3], rs[3];
    rc[0] = 145.801f * cosf(PI - 2.124f); rs[0] = 145.801f * sinf(PI - 2.124f);
    rc[1] = 152.326f * cosf(PI - 1.941f); rs[1] = 152.326f * sinf(PI - 1.941f);
    rc[2] = 132.868f * cosf(PI - 2.028f); rs[2] = 132.868f * sinf(PI - 2.028f);
    const int d0 = b % 3, d1 = (b + 2) % 3, d2 = (b + 1) % 3;
    rcl[0] = rc[d0]; rcl[1] = rc[d1]; rcl[2] = rc[d2];
    rsl[0] = rs[d0]; rsl[1] = rs[d1]; rsl[2] = rs[d2];
}

// Single-dispatch grid scan via flag lookback (no cooperative launch — R8
// showed hipLaunchCooperativeKernel no-ops under graph capture).
// Block = (g, btile): GROUP frags x BTILE b-lanes. All 256 blocks co-resident
// (1/CU) -> spin-wait cannot deadlock. Flags live in d_ws (poisoned 0xAA
// before every launch, != READY, so they self-reset).
__global__ void __launch_bounds__(GROUP * BTILE) coord_onepass(
    const float* __restrict__ dih, float* __restrict__ T,
    int* __restrict__ flags, float* __restrict__ out)
{
    const int btile = blockIdx.x & (NTILE - 1);
    const int g     = blockIdx.x >> 4;                 // NTILE==16
    const int bsub  = threadIdx.x & (BTILE - 1);
    const int j     = threadIdx.x >> 5;                // BTILE==32
    const int f     = g * GROUP + j;
    const int b     = btile * BTILE + bsub;

    __shared__ float S[GROUP * BTILE * 13];            // stride 13: conflict-free
    float* Srow = &S[(size_t)threadIdx.x * 13];

    float rcl[3], rsl[3];
    lane_consts(b, rcl, rsl);

    // ---- Stage 1: local chain, points kept in registers ----
    float lx[3 * RPF], ly[3 * RPF], lz[3 * RPF];

    float ax = -0.70710678118654752f, ay = 1.22474487139158905f, az = 0.0f;
    float bx = -1.41421356237309505f, by = 0.0f, bz = 0.0f;
    float cx = 0.0f, cy = 0.0f, cz = 0.0f;

    #pragma unroll
    for (int r = 0; r < RPF; ++r) {
        int l = f * RPF + r;
        const float* src = dih + (size_t)l * (3 * BATCH) + b;
        float dd[3];
        dd[0] = src[0];
        dd[1] = src[BATCH];
        dd[2] = src[2 * BATCH];
        #pragma unroll
        for (int k = 0; k < 3; ++k) {
            float sn, cs;
            __sincosf(dd[k], &sn, &cs);
            float ox, oy, oz;
            nerf_step(ax, ay, az, bx, by, bz, cx, cy, cz,
                      rcl[k], cs * rsl[k], sn * rsl[k], ox, oy, oz);
            ax = bx; ay = by; az = bz;
            bx = cx; by = cy; bz = cz;
            cx = ox; cy = oy; cz = oz;
            lx[r * 3 + k] = ox; ly[r * 3 + k] = oy; lz[r * 3 + k] = oz;
        }
    }

    {
        float h[12];
        frame_of(ax, ay, az, bx, by, bz, cx, cy, cz, h);
        #pragma unroll
        for (int k = 0; k < 12; ++k) Srow[k] = h[k];
    }
    __syncthreads();

    // ---- In-block Hillis-Steele inclusive scan over j (non-commutative) ----
    float tmp[12];
    #pragma unroll
    for (int o = 1; o < GROUP; o <<= 1) {
        const bool act = (j >= o);
        if (act) compose(&S[(size_t)(threadIdx.x - o * BTILE) * 13], Srow, tmp);
        __syncthreads();
        if (act) {
            #pragma unroll
            for (int k = 0; k < 12; ++k) Srow[k] = tmp[k];
        }
        __syncthreads();
    }

    // ---- Publish group total T_g (j==GROUP-1 rows), then release flag ----
    if (j == GROUP - 1) {
        #pragma unroll
        for (int k = 0; k < 12; ++k)
            __hip_atomic_store(&T[((size_t)g * 12 + k) * BATCH + b], Srow[k],
                               __ATOMIC_RELAXED, __HIP_MEMORY_SCOPE_AGENT);
    }
    __syncthreads();
    if (threadIdx.x == 0)
        __hip_atomic_store(&flags[g * NTILE + btile], READY,
                           __ATOMIC_RELEASE, __HIP_MEMORY_SCOPE_AGENT);

    // ---- Lookback: wait for all predecessor groups' totals ----
    if (g > 0) {
        if ((int)threadIdx.x < g) {
            while (__hip_atomic_load(&flags[threadIdx.x * NTILE + btile],
                                     __ATOMIC_ACQUIRE, __HIP_MEMORY_SCOPE_AGENT)
                   != READY) {
                __builtin_amdgcn_s_sleep(1);
            }
        }
        __syncthreads();
    }

    // ---- E_g = T_0 o ... o T_{g-1}; G = E_g o S[j-1] ----
    float G[12];
    if (g == 0) {
        G[0]=1.f; G[1]=0.f; G[2]=0.f;
        G[3]=0.f; G[4]=1.f; G[5]=0.f;
        G[6]=0.f; G[7]=0.f; G[8]=1.f;
        G[9]=0.f; G[10]=0.f; G[11]=0.f;
    } else {
        #pragma unroll
        for (int k = 0; k < 12; ++k)
            G[k] = __hip_atomic_load(&T[(size_t)k * BATCH + b],
                                     __ATOMIC_RELAXED, __HIP_MEMORY_SCOPE_AGENT);
        for (int gp = 1; gp < g; ++gp) {
            float tg[12];
            #pragma unroll
            for (int k = 0; k < 12; ++k)
                tg[k] = __hip_atomic_load(&T[((size_t)gp * 12 + k) * BATCH + b],
                                          __ATOMIC_RELAXED, __HIP_MEMORY_SCOPE_AGENT);
            compose(G, tg, G);
        }
    }
    if (j > 0) {
        // P[f-1] == inclusive prefix row of thread (j-1, bsub), still in LDS.
        compose(G, &S[(size_t)(threadIdx.x - BTILE) * 13], G);
    }

    // ---- Transform register-held points, coalesced stores ----
    #pragma unroll
    for (int q = 0; q < 3 * RPF; ++q) {
        float ox = lx[q], oy = ly[q], oz = lz[q];
        float gx = G[0]*ox + G[1]*oy + G[2]*oz + G[9];
        float gy = G[3]*ox + G[4]*oy + G[5]*oz + G[10];
        float gz = G[6]*ox + G[7]*oy + G[8]*oz + G[11];
        size_t n = (size_t)f * (3 * RPF) + q;            // scan step index
        float* dst = out + (n * BATCH + b) * 3;
        dst[0] = gx; dst[1] = gy; dst[2] = gz;
    }
}

extern "C" void kernel_launch(void* const* d_in, const int* in_sizes, int n_in,
                              void* d_out, int out_size, void* d_ws, size_t ws_size,
                              hipStream_t stream) {
    const float* dih = (const float*)d_in[0];
    float* out = (float*)d_out;
    float* T = (float*)d_ws;                           // NGRP*12*BATCH floats
    int* flags = (int*)(T + (size_t)NGRP * 12 * BATCH); // NGRP*NTILE ints

    coord_onepass<<<dim3(NGRP * NTILE), dim3(GROUP * BTILE), 0, stream>>>(
        dih, T, flags, out);
    (void)ws_size; (void)n_in; (void)out_size; (void)in_sizes;
}